// Round 9
// baseline (146.991 us; speedup 1.0000x reference)
//
#include <hip/hip_runtime.h>

// Levenshtein edit distance, ref (512,B) x hyp (512,B), B=1024, unit costs.
// Anti-diagonal wavefront, TWO waves per problem (128-thread block):
// wave w owns cells [256w, 256w+256), 4 cells/lane, parity-packed
// (reg p = cells {4l+p, 4l+p+2}), VOP3P via inline asm (r8 win).
// 2048 waves -> 2 waves/SIMD: co-resident waves fill each other's
// dependency stalls (r1-r8 evidence: 1 wave/SIMD is latency-bound).
//
// Biased relative domain (r7/r8-verified exact): w = v - d + 1024.
//   AN = min(a1s, A1, a2s + nq - 2), nq via min_u16(xor, 1).
// Token flow: block-shared padded LDS array; wave w injects hs[d-256w-2]
// (low pad = sentinels, high pad = last token == old clamp semantics).
// Value seam (cell 255 -> 256): CHUNKED. Wave0 runs 12 steps ahead,
// banks boundary dwords (hi half = top cell) via 3 ds_write_b128/chunk;
// wave1 reads 3 ds_read_b128/chunk and feeds them to the DPP old operand.
// Chunk-edge + A2 seams are carried renames. One __syncthreads / 12 steps.

#define HLEN 512
#define BATCH 1024
#define FAKE2  0x3FFF3FFFu  // packed fake-infinity (decays <=2/step, stays >1024)
#define SENT   0x000003FFu  // token sentinel (real tokens < 1000)
#define SENT2  0x03FF03FFu
#define BIASHI 0x04000000u  // 1024 in high half: DPP old for i=0 boundary
#define ONE2   0x00010001u
#define NEG22  0xFFFEFFFEu

// lane L gets src from lane L-1; lane 0 gets `old` (gfx9 DPP WAVE_SHR1).
__device__ __forceinline__ unsigned dpp_shr1(unsigned old, unsigned src) {
  return (unsigned)__builtin_amdgcn_update_dpp((int)old, (int)src, 0x138, 0xF, 0xF, false);
}
__device__ __forceinline__ unsigned algn(unsigned hi, unsigned lo) {
  return __builtin_amdgcn_alignbit(hi, lo, 16);
}
__device__ __forceinline__ unsigned pkmin(unsigned a, unsigned b) {
  unsigned d; asm("v_pk_min_u16 %0, %1, %2" : "=v"(d) : "v"(a), "v"(b)); return d;
}
__device__ __forceinline__ unsigned pkadd(unsigned a, unsigned b) {
  unsigned d; asm("v_pk_add_u16 %0, %1, %2" : "=v"(d) : "v"(a), "v"(b)); return d;
}

// One step. QP0 = tokens at even local cells {4l,4l+2}, QP1 = odd.
// Post: hn (new even tokens) stored into QP1's register -> SWAP args
// on the next call. Seam enters via OLDV (hi half = boundary value).
#define STEP(A2, A1, AN, QP0, QP1, OLDV, TOK)                        \
  {                                                                  \
    unsigned dA1 = dpp_shr1((OLDV), A1[1]);                          \
    unsigned a1s0 = algn(A1[1], dA1);                                \
    unsigned dHT = dpp_shr1((TOK) << 16, QP1);                       \
    unsigned hn = algn(QP1, dHT);                                    \
    unsigned nq0 = pkmin(rt0 ^ hn, one2);                            \
    unsigned c0  = pkadd(s0c, pkadd(nq0, neg2));                     \
    AN[0] = pkmin(pkmin(a1s0, A1[0]), c0);                           \
    unsigned nq1 = pkmin(rt1 ^ QP0, one2);                           \
    unsigned c1  = pkadd(A2[0], pkadd(nq1, neg2));                   \
    AN[1] = pkmin(pkmin(A1[0], A1[1]), c1);                          \
    s0c = a1s0;                                                      \
    QP1 = hn;                                                        \
  }

__global__ void __launch_bounds__(128)
edit_distance_kernel(const int* __restrict__ ref,
                     const int* __restrict__ hyp,
                     float* __restrict__ out) {
  const int b = blockIdx.x;
  const int tid = threadIdx.x;
  const int lane = tid & 63;
  const int wave = tid >> 6;           // 0: cells 0..255, 1: cells 256..511

  // Padded token array: hs[288+i] = hyp0[i]; low pad [0,288) = SENT
  // (pre-frontier, never equal); high pad [800,1332) = hyp0[511] (clamp).
  __shared__ unsigned hs[1332];
  __shared__ unsigned buf[2][12];      // seam ring: 2 chunks x 12 boundary dwords

  for (int i = tid; i < 288; i += 128) hs[i] = SENT;
  for (int i = tid; i < 512; i += 128) hs[288 + i] = (unsigned)hyp[i * BATCH + b];
  {
    unsigned last = (unsigned)hyp[511 * BATCH + b];
    for (int i = 800 + tid; i < 1332; i += 128) hs[i] = last;
  }
  if (tid < 24) ((unsigned*)buf)[tid] = FAKE2;

  // Parity-packed static ref tokens for local cells 4l+p, p+2.
  const int C = wave << 8;
  unsigned rt0, rt1;
  {
    unsigned e0 = (unsigned)ref[(C + 4 * lane + 0) * BATCH + b];
    unsigned e2 = (unsigned)ref[(C + 4 * lane + 2) * BATCH + b];
    unsigned e1 = (unsigned)ref[(C + 4 * lane + 1) * BATCH + b];
    unsigned e3 = (unsigned)ref[(C + 4 * lane + 3) * BATCH + b];
    rt0 = e0 | (e2 << 16);
    rt1 = e1 | (e3 << 16);
  }
  __syncthreads();  // hs + buf init visible

  const unsigned one2 = ONE2, neg2 = NEG22;
  unsigned A[2], Bv[2], Cv[2];
  A[0] = A[1] = Bv[0] = Bv[1] = FAKE2;
  unsigned q0 = SENT2, q1 = SENT2;
  unsigned s0c = FAKE2;        // carried shifted-A2 seam
  unsigned scarry = FAKE2;     // wave1: chunk-edge seam carry
  if (wave == 0 && lane == 0) {
    Bv[0] = 0x3FFF0400u;       // cell 0 on diag 1: w = 1024
    s0c   = 0x3FFF0400u;       // shifted diag 0: lane0 lo = 1024 boundary
  }

  // 86 chunks x 12 steps. Wave0: d = 2+12n+j. Wave1 lags 12: d = 12n-10+j.
  for (int n = 0; n < 86; ++n) {
    if (wave == 0) {
      const int tb = 288 + 12 * n;               // inject hyp0[d-2], d=2+12n+j
      uint4 ta = *((const uint4*)&hs[tb]);
      uint4 tm = *((const uint4*)&hs[tb + 4]);
      uint4 tc = *((const uint4*)&hs[tb + 8]);
      unsigned s0, s1, s2, s3, s4, s5, s6, s7, s8, s9, s10, s11;
      STEP(A, Bv, Cv, q0, q1, BIASHI, ta.x);  s0  = Cv[1];
      STEP(Bv, Cv, A, q1, q0, BIASHI, ta.y);  s1  = A[1];
      STEP(Cv, A, Bv, q0, q1, BIASHI, ta.z);  s2  = Bv[1];
      STEP(A, Bv, Cv, q1, q0, BIASHI, ta.w);  s3  = Cv[1];
      STEP(Bv, Cv, A, q0, q1, BIASHI, tm.x);  s4  = A[1];
      STEP(Cv, A, Bv, q1, q0, BIASHI, tm.y);  s5  = Bv[1];
      STEP(A, Bv, Cv, q0, q1, BIASHI, tm.z);  s6  = Cv[1];
      STEP(Bv, Cv, A, q1, q0, BIASHI, tm.w);  s7  = A[1];
      STEP(Cv, A, Bv, q0, q1, BIASHI, tc.x);  s8  = Bv[1];
      STEP(A, Bv, Cv, q1, q0, BIASHI, tc.y);  s9  = Cv[1];
      STEP(Bv, Cv, A, q0, q1, BIASHI, tc.z);  s10 = A[1];
      STEP(Cv, A, Bv, q1, q0, BIASHI, tc.w);  s11 = Bv[1];
      if (lane == 63) {                        // bank boundary values BW(2+12n+j)
        uint4* dst = (uint4*)&buf[n & 1][0];
        dst[0] = make_uint4(s0, s1, s2, s3);
        dst[1] = make_uint4(s4, s5, s6, s7);
        dst[2] = make_uint4(s8, s9, s10, s11);
      }
    } else {
      // Seam regs for this chunk: j=0 <- scarry (BW(12n-11)); j>=1 <- prev
      // chunk's buffer entries 0..10 (BW(12n-10+...)); new carry = entry 11.
      uint4 sa = *((const uint4*)&buf[(n + 1) & 1][0]);
      uint4 sb = *((const uint4*)&buf[(n + 1) & 1][4]);
      uint4 sc = *((const uint4*)&buf[(n + 1) & 1][8]);
      const int tb = 20 + 12 * n;                // 288 + (12n-10) - 258
      uint4 ta = *((const uint4*)&hs[tb]);
      uint4 tm = *((const uint4*)&hs[tb + 4]);
      uint4 tc = *((const uint4*)&hs[tb + 8]);
      STEP(A, Bv, Cv, q0, q1, scarry, ta.x);
      STEP(Bv, Cv, A, q1, q0, sa.x,   ta.y);
      STEP(Cv, A, Bv, q0, q1, sa.y,   ta.z);
      STEP(A, Bv, Cv, q1, q0, sa.z,   ta.w);
      STEP(Bv, Cv, A, q0, q1, sa.w,   tm.x);
      STEP(Cv, A, Bv, q1, q0, sb.x,   tm.y);
      STEP(A, Bv, Cv, q0, q1, sb.y,   tm.z);
      STEP(Bv, Cv, A, q1, q0, sb.z,   tm.w);
      STEP(Cv, A, Bv, q0, q1, sb.w,   tc.x);
      STEP(A, Bv, Cv, q1, q0, sc.x,   tc.y);
      STEP(Bv, Cv, A, q0, q1, sc.y,   tc.z);
      STEP(Cv, A, Bv, q1, q0, sc.z,   tc.w);
      scarry = sc.w;
    }
    __syncthreads();  // chunk handoff
  }

  // Epilogue: wave1 steps d = 1022, 1023, 1024 (chunk "86"; seams BW(1021)
  // = scarry, BW(1022)/BW(1023) = buf[1][0..1] written by wave0 at n=85,
  // visible after the loop's final barrier). Wave0 is done (no barriers here).
  if (wave == 1) {
    unsigned s0 = buf[1][0];
    unsigned s1 = buf[1][1];
    unsigned t0 = hs[20 + 12 * 86];     // = hs[1052..]: high-pad region
    unsigned t1 = hs[20 + 12 * 86 + 1];
    unsigned t2 = hs[20 + 12 * 86 + 2];
    STEP(A, Bv, Cv, q0, q1, scarry, t0);  // d = 1022
    STEP(Bv, Cv, A, q1, q0, s0,     t1);  // d = 1023
    STEP(Cv, A, Bv, q0, q1, s1,     t2);  // d = 1024
    // Answer: global cell 511 = lane 63, pair 1, HIGH half; at d=1024, w=v.
    if (lane == 63) out[b] = (float)(Bv[1] >> 16);
  }
}

extern "C" void kernel_launch(void* const* d_in, const int* in_sizes, int n_in,
                              void* d_out, int out_size, void* d_ws, size_t ws_size,
                              hipStream_t stream) {
  const int* ref = (const int*)d_in[0];
  const int* hyp = (const int*)d_in[1];
  float* out = (float*)d_out;
  edit_distance_kernel<<<BATCH, 128, 0, stream>>>(ref, hyp, out);
}

// Round 10
// 133.953 us; speedup vs baseline: 1.0973x; 1.0973x over previous
//
#include <hip/hip_runtime.h>

// Levenshtein edit distance, ref (512,B) x hyp (512,B), B=1024, unit costs.
// ONE 64-lane wave per problem; the 512-cell anti-diagonal is split into two
// TEMPORALLY SKEWED halves inside the wave (ILP=2, no barriers, no LDS seam):
//   lower: cells 0..255, lane l holds {4l+p, 4l+p+2} (p=0,1), wave_SHR1,
//          runs 12 steps AHEAD; banks its top-cell (255) dword per step.
//   upper: cells 256..511 LANE-REVERSED: lane l holds cells 256+4*(63-l)+q,
//          pairs {q0,q2},{q1,q3}, wave_SHL1 (cell u-1 lives at lane l+1);
//          lags 12 steps; its boundary lane is 63 == where lower's seam
//          register lives -> seam = banked register passed as DPP `old`.
// Biased relative domain (r7-r9-verified exact): w = v - d + 1024.
//   AN = min(a1s, A1, a2s + nq - 2), nq = min_u16(ref^hyp, 1).
// Tokens: LDS array, PRE-SHIFTED <<16 (DPP old wants hi half), prefetched
// one full 12-step chunk ahead into registers (r8's proven pattern).

#define HLEN 512
#define BATCH 1024
#define FAKE2  0x3FFF3FFFu  // packed fake-infinity (decays <=2/step; >=14313 at end)
#define SENT2  0x03FF03FFu  // packed sentinel tokens (real tokens < 1000)
#define SENTHI 0x03FF0000u  // pre-shifted sentinel token dword
#define BIASHI 0x04000000u  // 1024 in hi half: i=0 boundary via DPP old
#define ONE2   0x00010001u
#define NEG22  0xFFFEFFFEu

// lane i <- lane i-1; lane 0 <- old.  (WAVE_SHR1, HW-verified r3-r9)
__device__ __forceinline__ unsigned dpp_shr1(unsigned old, unsigned src) {
  return (unsigned)__builtin_amdgcn_update_dpp((int)old, (int)src, 0x138, 0xF, 0xF, false);
}
// lane i <- lane i+1; lane 63 <- old.  (WAVE_SHL1)
__device__ __forceinline__ unsigned dpp_shl1(unsigned old, unsigned src) {
  return (unsigned)__builtin_amdgcn_update_dpp((int)old, (int)src, 0x130, 0xF, 0xF, false);
}
__device__ __forceinline__ unsigned algn(unsigned hi, unsigned lo) {
  return __builtin_amdgcn_alignbit(hi, lo, 16);  // {lo: lo.hi, hi: hi.lo}
}
__device__ __forceinline__ unsigned pkmin(unsigned a, unsigned b) {
  unsigned d; asm("v_pk_min_u16 %0, %1, %2" : "=v"(d) : "v"(a), "v"(b)); return d;
}
__device__ __forceinline__ unsigned pkadd(unsigned a, unsigned b) {
  unsigned d; asm("v_pk_add_u16 %0, %1, %2" : "=v"(d) : "v"(a), "v"(b)); return d;
}

// Lower-half step (r9 wave0, verified): TOKD pre-shifted token dword.
#define STEP_L(A2, A1, AN, QP0, QP1, TOKD)                          \
  {                                                                 \
    unsigned dA1 = dpp_shr1(BIASHI, A1[1]);                         \
    unsigned a1s0 = algn(A1[1], dA1);                               \
    unsigned dHT = dpp_shr1((TOKD), QP1);                           \
    unsigned hn = algn(QP1, dHT);                                   \
    unsigned nq0 = pkmin(rl0 ^ hn, one2);                           \
    unsigned c0  = pkadd(s0cl, pkadd(nq0, neg2));                   \
    AN[0] = pkmin(pkmin(a1s0, A1[0]), c0);                          \
    unsigned nq1 = pkmin(rl1 ^ QP0, one2);                          \
    unsigned c1  = pkadd(A2[0], pkadd(nq1, neg2));                  \
    AN[1] = pkmin(pkmin(A1[0], A1[1]), c1);                         \
    s0cl = a1s0;                                                    \
    QP1 = hn;                                                       \
  }

// Upper-half step (lane-reversed, wave_shl1). SEAM: banked lower dword
// whose lane-63 hi half = cell 255's A1 value (only lane 63's old is used).
#define STEP_U(A2, A1, AN, QP0, QP1, TOKD, SEAM)                    \
  {                                                                 \
    unsigned dA1 = dpp_shl1((SEAM), A1[1]);                         \
    unsigned a1s0 = algn(A1[1], dA1);                               \
    unsigned dHT = dpp_shl1((TOKD), QP1);                           \
    unsigned hn = algn(QP1, dHT);                                   \
    unsigned nq0 = pkmin(ru0 ^ hn, one2);                           \
    unsigned c0  = pkadd(s0cu, pkadd(nq0, neg2));                   \
    AN[0] = pkmin(pkmin(a1s0, A1[0]), c0);                          \
    unsigned nq1 = pkmin(ru1 ^ QP0, one2);                          \
    unsigned c1  = pkadd(A2[0], pkadd(nq1, neg2));                  \
    AN[1] = pkmin(pkmin(A1[0], A1[1]), c1);                         \
    s0cu = a1s0;                                                    \
    QP1 = hn;                                                       \
  }

__global__ void __launch_bounds__(64)
edit_distance_kernel(const int* __restrict__ ref,
                     const int* __restrict__ hyp,
                     float* __restrict__ out) {
  const int b = blockIdx.x;
  const int lane = threadIdx.x;

  // Padded pre-shifted token array: hs[288+i] = hyp0[i]<<16.
  // Low pad [0,288) = sentinel (pre-frontier); high pad [800,1344) = last
  // token (clamp semantics, feeds only j>511 garbage cells — r9-verified).
  __shared__ __align__(16) unsigned hs[1344];
  for (int i = lane; i < 288; i += 64) hs[i] = SENTHI;
  for (int i = lane; i < 512; i += 64)
    hs[288 + i] = ((unsigned)hyp[i * BATCH + b]) << 16;
  {
    unsigned last = ((unsigned)hyp[511 * BATCH + b]) << 16;
    for (int i = 800 + lane; i < 1344; i += 64) hs[i] = last;
  }

  // Packed ref tokens. Lower: cells 4l+p. Upper (reversed): 256+4*(63-l)+q.
  unsigned rl0, rl1, ru0, ru1;
  {
    unsigned e0 = (unsigned)ref[(4 * lane + 0) * BATCH + b];
    unsigned e1 = (unsigned)ref[(4 * lane + 1) * BATCH + b];
    unsigned e2 = (unsigned)ref[(4 * lane + 2) * BATCH + b];
    unsigned e3 = (unsigned)ref[(4 * lane + 3) * BATCH + b];
    rl0 = e0 | (e2 << 16);
    rl1 = e1 | (e3 << 16);
    int ub = 256 + 4 * (63 - lane);
    unsigned f0 = (unsigned)ref[(ub + 0) * BATCH + b];
    unsigned f1 = (unsigned)ref[(ub + 1) * BATCH + b];
    unsigned f2 = (unsigned)ref[(ub + 2) * BATCH + b];
    unsigned f3 = (unsigned)ref[(ub + 3) * BATCH + b];
    ru0 = f0 | (f2 << 16);
    ru1 = f1 | (f3 << 16);
  }
  __syncthreads();

  const unsigned one2 = ONE2, neg2 = NEG22;

  // Lower DP state (diag init r9-verified): BL = diag 1, AL = diag 0.
  unsigned AL[2], BL[2], CL[2], AU[2], BU[2], CU[2];
  AL[0] = AL[1] = BL[0] = BL[1] = FAKE2;
  AU[0] = AU[1] = BU[0] = BU[1] = FAKE2;
  unsigned ql0 = SENT2, ql1 = SENT2, qu0 = SENT2, qu1 = SENT2;
  unsigned s0cl = FAKE2, s0cu = FAKE2;
  if (lane == 0) { BL[0] = 0x3FFF0400u; s0cl = 0x3FFF0400u; }

  // Seam FIFO in registers: sp0..sp11 = prev chunk's banked boundary dwords
  // (lower diags 2+12(n-1)+j), scarry = one older (diag 12n-11 consumer).
  unsigned sp0 = FAKE2, sp1 = FAKE2, sp2 = FAKE2, sp3 = FAKE2;
  unsigned sp4 = FAKE2, sp5 = FAKE2, sp6 = FAKE2, sp7 = FAKE2;
  unsigned sp8 = FAKE2, sp9 = FAKE2, sp10 = FAKE2, sp11 = FAKE2;
  unsigned scarry = FAKE2;

  // Token regs for current chunk (prefetched): lower idx 288+12n+j,
  // upper idx 20+12n+j (= 288 + (e-258), e = 12n+j-10).
  uint4 tla = *(const uint4*)&hs[288];
  uint4 tlb = *(const uint4*)&hs[292];
  uint4 tlc = *(const uint4*)&hs[296];
  uint4 tua = *(const uint4*)&hs[20];
  uint4 tub = *(const uint4*)&hs[24];
  uint4 tuc = *(const uint4*)&hs[28];

  // 86 chunks x 12 slots. Lower: d = 2+12n+j. Upper: e = 12n+j-10.
  for (int n = 0; n < 86; ++n) {
    const int lb = 288 + 12 * (n + 1);
    const int ub2 = 20 + 12 * (n + 1);
    uint4 nla = *(const uint4*)&hs[lb];
    uint4 nlb = *(const uint4*)&hs[lb + 4];
    uint4 nlc = *(const uint4*)&hs[lb + 8];
    uint4 nua = *(const uint4*)&hs[ub2];
    uint4 nub = *(const uint4*)&hs[ub2 + 4];
    uint4 nuc = *(const uint4*)&hs[ub2 + 8];
    unsigned sn0, sn1, sn2, sn3, sn4, sn5, sn6, sn7, sn8, sn9, sn10, sn11;

    STEP_L(AL, BL, CL, ql0, ql1, tla.x); sn0 = CL[1];
    STEP_U(AU, BU, CU, qu0, qu1, tua.x, scarry);
    STEP_L(BL, CL, AL, ql1, ql0, tla.y); sn1 = AL[1];
    STEP_U(BU, CU, AU, qu1, qu0, tua.y, sp0);
    STEP_L(CL, AL, BL, ql0, ql1, tla.z); sn2 = BL[1];
    STEP_U(CU, AU, BU, qu0, qu1, tua.z, sp1);
    STEP_L(AL, BL, CL, ql1, ql0, tla.w); sn3 = CL[1];
    STEP_U(AU, BU, CU, qu1, qu0, tua.w, sp2);
    STEP_L(BL, CL, AL, ql0, ql1, tlb.x); sn4 = AL[1];
    STEP_U(BU, CU, AU, qu0, qu1, tub.x, sp3);
    STEP_L(CL, AL, BL, ql1, ql0, tlb.y); sn5 = BL[1];
    STEP_U(CU, AU, BU, qu1, qu0, tub.y, sp4);
    STEP_L(AL, BL, CL, ql0, ql1, tlb.z); sn6 = CL[1];
    STEP_U(AU, BU, CU, qu0, qu1, tub.z, sp5);
    STEP_L(BL, CL, AL, ql1, ql0, tlb.w); sn7 = AL[1];
    STEP_U(BU, CU, AU, qu1, qu0, tub.w, sp6);
    STEP_L(CL, AL, BL, ql0, ql1, tlc.x); sn8 = BL[1];
    STEP_U(CU, AU, BU, qu0, qu1, tuc.x, sp7);
    STEP_L(AL, BL, CL, ql1, ql0, tlc.y); sn9 = CL[1];
    STEP_U(AU, BU, CU, qu1, qu0, tuc.y, sp8);
    STEP_L(BL, CL, AL, ql0, ql1, tlc.z); sn10 = AL[1];
    STEP_U(BU, CU, AU, qu0, qu1, tuc.z, sp9);
    STEP_L(CL, AL, BL, ql1, ql0, tlc.w); sn11 = BL[1];
    STEP_U(CU, AU, BU, qu1, qu0, tuc.w, sp10);

    // FIFO shift: next chunk's scarry = this chunk's consumed sp11 holder
    // (diag 12n+1); sp <- freshly banked (diags 2+12n .. 13+12n).
    scarry = sp11;
    sp0 = sn0; sp1 = sn1; sp2 = sn2; sp3 = sn3; sp4 = sn4; sp5 = sn5;
    sp6 = sn6; sp7 = sn7; sp8 = sn8; sp9 = sn9; sp10 = sn10; sp11 = sn11;
    tla = nla; tlb = nlb; tlc = nlc;
    tua = nua; tub = nub; tuc = nuc;
  }

  // Upper epilogue: e = 1022, 1023, 1024. Seams: diag 1021 = scarry
  // (chunk-84 sp11), 1022 = sp0, 1023 = sp1 (chunk-85 banked). Tokens:
  // prefetched "chunk 86" upper regs = hs[1052..] = hyp0[764..]<<16.
  STEP_U(AU, BU, CU, qu0, qu1, tua.x, scarry);  // e = 1022
  STEP_U(BU, CU, AU, qu1, qu0, tua.y, sp0);     // e = 1023
  STEP_U(CU, AU, BU, qu0, qu1, tua.z, sp1);     // e = 1024

  // Answer: global cell 511 = upper u=255 = lane 0, pair1 HIGH half.
  // At d = 1024 = BIAS, w = v exactly.
  if (lane == 0) out[b] = (float)(BU[1] >> 16);
}

extern "C" void kernel_launch(void* const* d_in, const int* in_sizes, int n_in,
                              void* d_out, int out_size, void* d_ws, size_t ws_size,
                              hipStream_t stream) {
  const int* ref = (const int*)d_in[0];
  const int* hyp = (const int*)d_in[1];
  float* out = (float*)d_out;
  edit_distance_kernel<<<BATCH, 64, 0, stream>>>(ref, hyp, out);
}